// Round 1
// 513.014 us; speedup vs baseline: 1.0219x; 1.0219x over previous
//
#include <hip/hip_runtime.h>

#define BIMG 8
#define NBOX 100000
#define NCLS 80
#define KDET 300
#define CAP  2048
#define CAPC 20                 // per-block per-class LDS staging capacity
#define TPUSH 0.984375f         // common-path push threshold (126/128)
#define SCORE_T 0.05f
#define NELEM 8000000           // N*C per image
#define NQ    2000000           // float4s per image

typedef unsigned long long u64;
typedef unsigned u32;

// workspace layout (bytes)
#define OFF_PUSHCNT 0u              // 640*4 = 2560
#define ZERO_BYTES  2560u
#define OFF_BUF     4096u           // 640*2048*8 = 10485760
#define OFF_KCNT    (4096u + 10485760u)     // 640*4
#define OFF_KSC     (OFF_KCNT + 2560u)      // 640*300*4
#define OFF_KIDX    (OFF_KSC + 768000u)     // 640*300*4

static __device__ __forceinline__ u64 mk_key(float sc, u32 n) {
  return ((u64)__float_as_uint(sc) << 32) | (u32)(~n);
}

// One radix-select step over `hist[nbins]` (single copy), executed by wave 0.
// Finds bin of the sk-th largest (counting from top), updates spfx/sk.
// Caller must __syncthreads() before and after. Writes total into *stot (lane0).
static __device__ __forceinline__ void radix_step(const u32* hist, int nbins,
                                                  int width, u32* sk, u64* spfx,
                                                  u32* stot) {
  if (threadIdx.x < 64) {
    const int lane = threadIdx.x;
    const int chunk = nbins >> 6;
    u32 psum = 0;
    for (int i = 0; i < chunk; ++i) psum += hist[lane * chunk + i];
    u32 suf = psum;
#pragma unroll
    for (int off = 1; off < 64; off <<= 1) {
      u32 o = __shfl_down(suf, off);
      if (lane + off < 64) suf += o;
    }
    if (lane == 0) *stot = suf;          // lane0 suffix == total
    u32 k = *sk;
    u64 bal = __ballot(suf >= k);
    if (bal != 0ull) {
      int L = 63 - __clzll((long long)bal);
      if (lane == L) {
        u32 krem = k - (suf - psum);     // remaining within this chunk (from top)
        int bi = (L + 1) * chunk - 1;
        u32 acc = 0;
        for (;;) {
          acc += hist[bi];
          if (acc >= krem || bi == L * chunk) break;
          --bi;
        }
        *spfx = (*spfx << width) | (u32)bi;
        *sk = krem - (acc - hist[bi]);
      }
    }
  }
}

__constant__ int RSH[6] = {53, 42, 31, 20, 9, 0};
__constant__ int RWD[6] = {11, 11, 11, 11, 11, 9};

// ---------------- pass A: threshold push with block-local aggregation ----------------
static __device__ __forceinline__ void pushone(int c, float sc, u32 n, int b,
                                               u32* lcnt, u64* stage,
                                               u32* pushcnt, u64* buf) {
  u64 key = mk_key(sc, n);
  u32 slot = atomicAdd(&lcnt[c], 1u);
  if (slot < CAPC) {
    stage[c * CAPC + slot] = key;
  } else {    // rare LDS-staging overflow: direct global push
    u32 g = atomicAdd(&pushcnt[b * NCLS + c], 1u);
    if (g < CAP) buf[(size_t)(b * NCLS + c) * CAP + g] = key;
  }
}

__global__ __launch_bounds__(256) void histK(const float* __restrict__ cls,
                                             u32* __restrict__ pushcnt,
                                             u64* __restrict__ buf) {
  __shared__ u32 lcnt[NCLS];
  __shared__ u32 sbase[NCLS];
  __shared__ u64 stage[NCLS * CAPC];   // 12.8 KB

  const int t = threadIdx.x;
  const int b = blockIdx.y;
  for (int i = t; i < NCLS; i += 256) lcnt[i] = 0;
  __syncthreads();

  const float4* base4 = (const float4*)(cls + (size_t)b * NELEM);
  const int start = blockIdx.x * 8192;   // 245 blocks/img * 8192 float4 >= 2M

#define PROCQ(u) do { \
    float mx = fmaxf(fmaxf(v##u.x, v##u.y), fmaxf(v##u.z, v##u.w)); \
    if (mx >= TPUSH) { \
      const int e0 = q##u * 4; \
      const int c0 = e0 % NCLS; \
      const u32 n = (u32)(e0 / NCLS); \
      if (v##u.x >= TPUSH) pushone(c0 + 0, v##u.x, n, b, lcnt, stage, pushcnt, buf); \
      if (v##u.y >= TPUSH) pushone(c0 + 1, v##u.y, n, b, lcnt, stage, pushcnt, buf); \
      if (v##u.z >= TPUSH) pushone(c0 + 2, v##u.z, n, b, lcnt, stage, pushcnt, buf); \
      if (v##u.w >= TPUSH) pushone(c0 + 3, v##u.w, n, b, lcnt, stage, pushcnt, buf); \
    } } while (0)

  if (start + 8192 <= NQ) {            // full blocks: no bounds checks
    for (int it = 0; it < 4; ++it) {
      const int qb = start + it * 2048 + t;
#define LOADF(u) const int q##u = qb + (u) * 256; const float4 v##u = base4[q##u]
      LOADF(0); LOADF(1); LOADF(2); LOADF(3);
      LOADF(4); LOADF(5); LOADF(6); LOADF(7);
#undef LOADF
      PROCQ(0); PROCQ(1); PROCQ(2); PROCQ(3);
      PROCQ(4); PROCQ(5); PROCQ(6); PROCQ(7);
    }
  } else {                              // tail block: checked loads
    for (int it = 0; it < 4; ++it) {
      const int qb = start + it * 2048 + t;
#define LOADC(u) const int q##u = qb + (u) * 256; \
  const float4 v##u = (q##u < NQ) ? base4[q##u] : make_float4(0.f, 0.f, 0.f, 0.f)
      LOADC(0); LOADC(1); LOADC(2); LOADC(3);
      LOADC(4); LOADC(5); LOADC(6); LOADC(7);
#undef LOADC
      PROCQ(0); PROCQ(1); PROCQ(2); PROCQ(3);
      PROCQ(4); PROCQ(5); PROCQ(6); PROCQ(7);
    }
  }
#undef PROCQ
  __syncthreads();

  // one global atomic per (block, class) to reserve a contiguous range
  if (t < NCLS) {
    u32 cnt = min(lcnt[t], (u32)CAPC);
    sbase[t] = cnt ? atomicAdd(&pushcnt[b * NCLS + t], cnt) : 0u;
  }
  __syncthreads();
  for (int idx = t; idx < NCLS * CAPC; idx += 256) {
    const int c = idx / CAPC;
    const int k = idx - c * CAPC;
    if ((u32)k < min(lcnt[c], (u32)CAPC)) {
      u32 s = sbase[c] + (u32)k;
      if (s < CAP) buf[(size_t)(b * NCLS + c) * CAP + s] = stage[idx];
    }
  }
}

// ---------------- per (b,c): fallback (fused, rare) + radix top-300 + sort-512
// + NMS + compact ----------------
__global__ __launch_bounds__(512) void nmsK(const float* __restrict__ boxes,
                                            const float* __restrict__ cls,
                                            const u32* __restrict__ pushcnt,
                                            u64* __restrict__ buf,
                                            u32* __restrict__ keptCnt,
                                            float* __restrict__ keptScore,
                                            u32* __restrict__ keptIdx) {
  __shared__ float bx[KDET][4];                 // 4.8 KB
  __shared__ float scl[KDET];
  __shared__ u32 nn_[KDET];
  __shared__ u64 msk[KDET][5];                  // 12 KB (aliased as hist early)
  __shared__ u64 tk[512];                       // 4 KB
  __shared__ u64 keptw[5];
  __shared__ u64 spfx;
  __shared__ u32 sk, stot, stcnt;
  __shared__ u32 sfpfx, sfk, sfab, sfeq, sfmode, sfbcnt;

  const int t = threadIdx.x;
  const int bc = blockIdx.x;
  const int b = bc / NCLS;
  u64* bufp = buf + (size_t)bc * CAP;
  u32* hist = (u32*)&msk[0][0];   // 2048-bin scratch, dead before masks are built

  if (t == 0) { spfx = 0ull; sk = KDET; stcnt = 0u; sfmode = 0u; sfbcnt = 0u; }

  // ---- fused exact fallback (never taken on common inputs) ----
  u32 realcnt = pushcnt[bc];
  const bool dofb = !(realcnt >= (u32)KDET && realcnt <= (u32)CAP);
  if (dofb) {
    const int c = bc % NCLS;
    const float* col = cls + (size_t)b * NELEM + c;
    // MSD radix-select of the 300th-largest score-bits
    for (int r = 0; r < 3; ++r) {
      const int shift = (r == 0) ? 21 : (r == 1) ? 10 : 0;
      const int nbins = (r == 2) ? 1024 : 2048;
      for (int i = t; i < nbins; i += 512) hist[i] = 0;
      __syncthreads();
      for (int n = t; n < NBOX; n += 512) {
        float sc = col[(size_t)n * NCLS];
        if (sc > SCORE_T) {
          u32 u = __float_as_uint(sc);
          bool ok = (r == 0) || (r == 1 ? ((u >> 21) == (sfpfx >> 21))
                                        : ((u >> 10) == (sfpfx >> 10)));
          if (ok) atomicAdd(&hist[(u >> shift) & (u32)(nbins - 1)], 1u);
        }
      }
      __syncthreads();
      if (t == 0) {
        if (r == 0) {
          u32 s = 0;
          for (int i = 0; i < nbins; ++i) s += hist[i];
          if (s < KDET) sfmode = 1u;   // fewer than 300 candidates: push all
        }
        if (sfmode == 0u) {
          u32 kk2 = (r == 0) ? (u32)KDET : sfk;
          u32 acc = 0;
          int bi = nbins - 1;
          for (; bi >= 0; --bi) {
            if (acc + hist[bi] >= kk2) break;
            acc += hist[bi];
          }
          sfk = kk2 - acc;
          sfpfx = ((r == 0) ? 0u : sfpfx) | ((u32)bi << shift);
          if (r == 2) { sfeq = hist[bi]; sfab = KDET - sfk; }
        }
      }
      __syncthreads();
      if (sfmode == 1u) break;
    }

    if (sfmode == 1u) {
      for (int n = t; n < NBOX; n += 512) {
        float sc = col[(size_t)n * NCLS];
        if (sc > SCORE_T) {
          u32 g = atomicAdd(&sfbcnt, 1u);
          if (g < CAP) bufp[g] = mk_key(sc, (u32)n);
        }
      }
    } else {
      const u32 ustar = sfpfx;
      const u32 m = sfab, e = sfeq;
      if (m + e <= CAP) {
        for (int n = t; n < NBOX; n += 512) {
          float sc = col[(size_t)n * NCLS];
          if (sc > SCORE_T && __float_as_uint(sc) >= ustar) {
            u32 g = atomicAdd(&sfbcnt, 1u);
            if (g < CAP) bufp[g] = mk_key(sc, (u32)n);
          }
        }
      } else {
        for (int n = t; n < NBOX; n += 512) {
          float sc = col[(size_t)n * NCLS];
          if (sc > SCORE_T && __float_as_uint(sc) > ustar) {
            u32 g = atomicAdd(&sfbcnt, 1u);
            if (g < CAP) bufp[g] = mk_key(sc, (u32)n);
          }
        }
        __syncthreads();
        if (t == 0) {
          u32 room = CAP - m, got = 0;
          for (int n = 0; n < NBOX && got < room; ++n) {
            float sc = col[(size_t)n * NCLS];
            if (sc > SCORE_T && __float_as_uint(sc) == ustar) {
              u32 g = atomicAdd(&sfbcnt, 1u);
              if (g < CAP) bufp[g] = mk_key(sc, (u32)n);
              ++got;
            }
          }
        }
      }
    }
    __threadfence_block();
    __syncthreads();
    realcnt = sfbcnt;
  }
  const int cnt = min((int)realcnt, CAP);

  u64 kk[4];
#pragma unroll
  for (int u = 0; u < 4; ++u) {
    int i = t + u * 512;
    u64 v = 0ull;
    if (i < cnt)
      v = dofb ? *((volatile const u64*)(bufp + i)) : bufp[i];   // L1-bypass on rare path
    kk[u] = v;
  }

  const bool normal = (cnt > KDET);   // block-uniform
  if (normal) {
    for (int p = 0; p < 6; ++p) {
      const int nb = (p == 5) ? 512 : 2048;
      for (int i = t; i < nb; i += 512) hist[i] = 0;
      __syncthreads();
      const u64 pfx = spfx;
#pragma unroll
      for (int u = 0; u < 4; ++u) {
        u64 key = kk[u];
        if (!key) continue;
        if (p > 0 && (key >> RSH[p - 1]) != pfx) continue;
        atomicAdd(&hist[(u32)(key >> RSH[p]) & (u32)(nb - 1)], 1u);
      }
      __syncthreads();
      radix_step(hist, nb, RWD[p], &sk, &spfx, &stot);
      __syncthreads();
    }
  } else {
    __syncthreads();
  }
  const u64 thr = normal ? spfx : 1ull;   // exact 300th-largest key (keys unique)

  tk[t] = 0ull;
  __syncthreads();
#pragma unroll
  for (int u = 0; u < 4; ++u) {
    u64 key = kk[u];
    if (key >= thr && key != 0ull) {
      u32 pos = atomicAdd(&stcnt, 1u);
      if (pos < 512) tk[pos] = key;
    }
  }
  __syncthreads();

  // ---- bitonic sort 512 descending, hybrid register/LDS form ----
  // strides j<=32 run as __shfl_xor within the wave (barrier-free); j>=64 via LDS.
  u64 a = tk[t];
#pragma unroll
  for (int k2 = 2; k2 <= 64; k2 <<= 1) {
#pragma unroll
    for (int j = k2 >> 1; j > 0; j >>= 1) {
      u64 c2 = __shfl_xor(a, j);
      bool takeMax = (((t & k2) == 0) == ((t & j) == 0));
      u64 mx = (a > c2) ? a : c2;
      u64 mn = (a > c2) ? c2 : a;
      a = takeMax ? mx : mn;
    }
  }
#pragma unroll
  for (int k2 = 128; k2 <= 512; k2 <<= 1) {
    for (int j = k2 >> 1; j >= 64; j >>= 1) {
      tk[t] = a;
      __syncthreads();
      u64 c2 = tk[t ^ j];
      bool takeMax = (((t & k2) == 0) == ((t & j) == 0));
      u64 mx = (a > c2) ? a : c2;
      u64 mn = (a > c2) ? c2 : a;
      a = takeMax ? mx : mn;
      __syncthreads();
    }
#pragma unroll
    for (int j = 32; j > 0; j >>= 1) {
      u64 c2 = __shfl_xor(a, j);
      bool takeMax = (((t & k2) == 0) == ((t & j) == 0));
      u64 mx = (a > c2) ? a : c2;
      u64 mn = (a > c2) ? c2 : a;
      a = takeMax ? mx : mn;
    }
  }
  tk[t] = a;
  __syncthreads();

  const int M = min((int)stcnt, KDET);
  for (int i = t; i < M; i += 512) {
    u64 key = tk[i];
    u32 n = ~(u32)key;
    scl[i] = __uint_as_float((u32)(key >> 32));
    nn_[i] = n;
    const float4 bv = *(const float4*)(boxes + ((size_t)b * NBOX + n) * 4);
    bx[i][0] = bv.x; bx[i][1] = bv.y; bx[i][2] = bv.z; bx[i][3] = bv.w;
  }
  __syncthreads();

  // suppression masks: bit j of msk[i] set iff IoU(box_i, box_j) >= 0.5, j < i
  for (int i = t; i < M; i += 512) {
    float x1 = bx[i][0], y1 = bx[i][1], x2 = bx[i][2], y2 = bx[i][3];
    float a1 = (x2 - x1) * (y2 - y1);
    u64 m0 = 0, m1 = 0, m2 = 0, m3 = 0, m4 = 0;
    for (int j = 0; j < i; ++j) {
      float lx = fmaxf(x1, bx[j][0]);
      float ly = fmaxf(y1, bx[j][1]);
      float rx = fminf(x2, bx[j][2]);
      float ry = fminf(y2, bx[j][3]);
      float iw = fmaxf(rx - lx, 0.0f), ih = fmaxf(ry - ly, 0.0f);
      float inter = iw * ih;
      float a2 = (bx[j][2] - bx[j][0]) * (bx[j][3] - bx[j][1]);
      float uni = fmaxf(a1 + a2 - inter, 1e-7f);
      float iou = inter / uni;   // true IEEE division: matches reference rounding
      if (iou >= 0.5f) {
        u64 bit = 1ull << (j & 63);
        switch (j >> 6) {
          case 0: m0 |= bit; break;
          case 1: m1 |= bit; break;
          case 2: m2 |= bit; break;
          case 3: m3 |= bit; break;
          default: m4 |= bit; break;
        }
      }
    }
    msk[i][0] = m0; msk[i][1] = m1; msk[i][2] = m2; msk[i][3] = m3; msk[i][4] = m4;
  }
  __syncthreads();

  // ---- wave-parallel greedy NMS scan (monotone-ballot) ----
  // Suppression predicate only flips 1->0 as the kept set grows, so the lowest
  // set bit of each ballot is final: one iteration per kept box.
  if (t < 64) {
    u64 kwv[5];
#pragma unroll
    for (int w = 0; w < 5; ++w) {
      const int i = w * 64 + t;
      bool pb = (i < M);
      u64 mown = 0ull;
      if (pb) {
#pragma unroll
        for (int w2 = 0; w2 < 5; ++w2)
          if (w2 < w && (msk[i][w2] & kwv[w2])) pb = false;
        mown = msk[i][w];
      }
      u64 kv = 0ull;
      for (;;) {
        u64 bal = __ballot(pb && ((mown & kv) == 0ull));
        if (!bal) break;
        int p = __ffsll((unsigned long long)bal) - 1;
        kv |= 1ull << p;
        if (t == p) pb = false;
      }
      kwv[w] = kv;
      if (t == 0) keptw[w] = kv;
    }
  }
  __syncthreads();

  for (int i = t; i < M; i += 512) {
    if ((keptw[i >> 6] >> (i & 63)) & 1ull) {
      int rank = 0;
      for (int w = 0; w < (i >> 6); ++w) rank += __popcll(keptw[w]);
      rank += __popcll(keptw[i >> 6] & ((1ull << (i & 63)) - 1ull));
      keptScore[(size_t)bc * KDET + rank] = scl[i];
      keptIdx[(size_t)bc * KDET + rank] = nn_[i];
    }
  }
  if (t == 0) {
    int tot = 0;
    for (int w = 0; w < 5; ++w) tot += __popcll(keptw[w]);
    keptCnt[bc] = (u32)tot;
  }
}

// ---------------- per image: parallel radix top-300 across all classes ----------------
#define MSLOT 24   // ceil(80*300/1024)
__global__ __launch_bounds__(1024) void mergeK(const float* __restrict__ boxes,
                                               const u32* __restrict__ keptCnt,
                                               const float* __restrict__ keptScore,
                                               const u32* __restrict__ keptIdx,
                                               float* __restrict__ out) {
  __shared__ u32 hist[4 * 2048];   // 32 KB, 4 privatized copies
  __shared__ int scnt[NCLS];
  __shared__ u64 tk[512];
  __shared__ u64 spfx, sthr;
  __shared__ u32 sk, stot, smode, stcnt;

  const int t = threadIdx.x;
  const int b = blockIdx.x;
  if (t < NCLS) scnt[t] = min((int)keptCnt[b * NCLS + t], KDET);
  if (t == 0) { spfx = 0ull; sk = KDET; smode = 0u; stcnt = 0u; }
  __syncthreads();

  // keys (score_bits<<32)|~(c*KDET+r) in registers; 0 = invalid
  u64 kk[MSLOT];
  const float* ksc = keptScore + (size_t)b * NCLS * KDET;
#pragma unroll
  for (int u = 0; u < MSLOT; ++u) {
    int idx = t + u * 1024;
    u64 key = 0ull;
    if (idx < NCLS * KDET) {
      int c = idx / KDET, r = idx - c * KDET;
      if (r < scnt[c])
        key = ((u64)__float_as_uint(ksc[idx]) << 32) | (u32)(~(u32)idx);
    }
    kk[u] = key;
  }

  for (int p = 0; p < 6; ++p) {
    const int nb = (p == 5) ? 512 : 2048;
    for (int i = t; i < 4 * 2048; i += 1024) hist[i] = 0;
    __syncthreads();
    u32* hp = hist + ((t >> 8) & 3) * 2048;
    const u64 pfx = spfx;
#pragma unroll
    for (int u = 0; u < MSLOT; ++u) {
      u64 key = kk[u];
      if (!key) continue;
      if (p > 0 && (key >> RSH[p - 1]) != pfx) continue;
      atomicAdd(&hp[(u32)(key >> RSH[p]) & (u32)(nb - 1)], 1u);
    }
    __syncthreads();
    for (int i = t; i < nb; i += 1024)
      hist[i] = hist[i] + hist[2048 + i] + hist[4096 + i] + hist[6144 + i];
    __syncthreads();
    radix_step(hist, nb, RWD[p], &sk, &spfx, &stot);
    __syncthreads();
    if (p == 0) {
      if (t == 0 && stot <= KDET) smode = 1u;
      __syncthreads();
      if (smode) break;
    }
  }
  if (t == 0) sthr = smode ? 1ull : spfx;
  if (t < 512) tk[t] = 0ull;
  __syncthreads();

  const u64 thr = sthr;
#pragma unroll
  for (int u = 0; u < MSLOT; ++u) {
    u64 key = kk[u];
    if (key >= thr && key != 0ull) {
      u32 pos = atomicAdd(&stcnt, 1u);
      if (pos < 512) tk[pos] = key;
    }
  }
  __syncthreads();

  // bitonic sort 512 descending
  for (int k2 = 2; k2 <= 512; k2 <<= 1) {
    for (int j = k2 >> 1; j > 0; j >>= 1) {
      if (t < 512) {
        int i = t, ixj = i ^ j;
        if (ixj > i) {
          u64 a = tk[i], c2 = tk[ixj];
          bool up = ((i & k2) == 0);
          if (up ? (a < c2) : (a > c2)) { tk[i] = c2; tk[ixj] = a; }
        }
      }
      __syncthreads();
    }
  }

  // outputs: boxes [B,K,4] | scores [B,K] | labels [B,K] (as float)
  if (t < KDET) {
    float* ob = out + ((size_t)b * KDET + t) * 4;
    float* os = out + (size_t)BIMG * KDET * 4;
    float* ol = os + (size_t)BIMG * KDET;
    u64 key = tk[t];
    if (key == 0ull) {
      *(float4*)ob = make_float4(-1.f, -1.f, -1.f, -1.f);
      os[(size_t)b * KDET + t] = -1.f;
      ol[(size_t)b * KDET + t] = -1.f;
    } else {
      u32 fi = ~(u32)key;
      int c = fi / KDET, r = fi - c * KDET;
      u32 n = keptIdx[((size_t)b * NCLS + c) * KDET + r];
      *(float4*)ob = *(const float4*)(boxes + ((size_t)b * NBOX + n) * 4);
      os[(size_t)b * KDET + t] = __uint_as_float((u32)(key >> 32));
      ol[(size_t)b * KDET + t] = (float)c;
    }
  }
}

extern "C" void kernel_launch(void* const* d_in, const int* in_sizes, int n_in,
                              void* d_out, int out_size, void* d_ws, size_t ws_size,
                              hipStream_t stream) {
  const float* boxes = (const float*)d_in[0];
  const float* cls = (const float*)d_in[1];
  float* out = (float*)d_out;
  char* ws = (char*)d_ws;

  u32* pushcnt = (u32*)(ws + OFF_PUSHCNT);
  u64* buf = (u64*)(ws + OFF_BUF);
  u32* keptCnt = (u32*)(ws + OFF_KCNT);
  float* keptScore = (float*)(ws + OFF_KSC);
  u32* keptIdx = (u32*)(ws + OFF_KIDX);

  (void)hipMemsetAsync(ws + OFF_PUSHCNT, 0, ZERO_BYTES, stream);

  histK<<<dim3(245, BIMG), 256, 0, stream>>>(cls, pushcnt, buf);
  nmsK<<<BIMG * NCLS, 512, 0, stream>>>(boxes, cls, pushcnt, buf, keptCnt,
                                        keptScore, keptIdx);
  mergeK<<<BIMG, 1024, 0, stream>>>(boxes, keptCnt, keptScore, keptIdx, out);
}